// Round 5
// baseline (165.365 us; speedup 1.0000x reference)
//
#include <hip/hip_runtime.h>

// HandcraftedPodExtractor: 3D cell binning + normalized feature vector.
// Input  x: (64, 65536, 6) fp32  [pos(3) | ori(3)] interleaved per point.
// Output  : (64, 640) fp32.
//
// R4 accounting: ~92us of the timed window is harness ws-poison (402MB
// fill, 59.5us) + input restore (~32us). k_bin ~25us. Residual ~50us is
// k_bbox at ~2.3 TB/s — 3x off BW ceiling. Theory: 48-B-strided dwordx4
// loads (3 consecutive float4 per thread) throttle the TA/L1 path.
// R5: k_bbox rewritten with unit-stride float4 loads (1 KB/wave/instr,
// perfect coalescing); position components extracted via mask rotating
// with (tid%3 + it) % 3. k_bin/k_final unchanged (single-variable test).
//
// Fixed-point scales:
//   offsets: round(off * 2^18)  (|off|<=~0.13 -> per-pt<2^15, blk-sum<2^27)
//   cov:     round(v  * 2^12)  (per-pt<2^18 at 5.6-sigma, blk-sum<2^31)
// Output quantization error ~1e-6..1e-4, threshold 5.9e-3.
//
// ws layout:
//   [0,    4096)           : part_max[B*16] as uint bits (nonneg floats)
//   [4096, 4096 + 327680)  : acc[B][640] int64

#define BATCH 64
#define NPTS 65536
#define FEAT 640          // 64 cells * 10 values
#define COPIES 16         // replicated LDS histograms (lane % 16)
#define CSTRIDE 17        // padded copy stride -> 16 distinct banks per slot
#define S_OFF 262144.0f   // 2^18
#define S_COV 4096.0f     // 2^12

__device__ __forceinline__ void bin_point(int* h, int k,
                                          float px, float py, float pz,
                                          float ox, float oy, float oz,
                                          float bmax, float inv_thick) {
    float sx = (px + bmax) * inv_thick;
    float sy = (py + bmax) * inv_thick;
    float sz = (pz + bmax) * inv_thick;
    int cx = (int)(sx * 4.0f); cx = cx < 0 ? 0 : (cx > 3 ? 3 : cx);
    int cy = (int)(sy * 4.0f); cy = cy < 0 ? 0 : (cy > 3 ? 3 : cy);
    int cz = (int)(sz * 4.0f); cz = cz < 0 ? 0 : (cz > 3 ? 3 : cz);
    int cell = (cx * 4 + cy) * 4 + cz;
    float offx = sx - (cx * 0.25f + 0.125f);
    float offy = sy - (cy * 0.25f + 0.125f);
    float offz = sz - (cz * 0.25f + 0.125f);
    int a = cell * (10 * CSTRIDE) + k;
    atomicAdd(&h[a + 0 * CSTRIDE], 1);
    atomicAdd(&h[a + 1 * CSTRIDE], __float2int_rn(offx * S_OFF));
    atomicAdd(&h[a + 2 * CSTRIDE], __float2int_rn(offy * S_OFF));
    atomicAdd(&h[a + 3 * CSTRIDE], __float2int_rn(offz * S_OFF));
    atomicAdd(&h[a + 4 * CSTRIDE], __float2int_rn(ox * ox * S_COV));
    atomicAdd(&h[a + 5 * CSTRIDE], __float2int_rn(ox * oy * S_COV));
    atomicAdd(&h[a + 6 * CSTRIDE], __float2int_rn(ox * oz * S_COV));
    atomicAdd(&h[a + 7 * CSTRIDE], __float2int_rn(oy * oy * S_COV));
    atomicAdd(&h[a + 8 * CSTRIDE], __float2int_rn(oy * oz * S_COV));
    atomicAdd(&h[a + 9 * CSTRIDE], __float2int_rn(oz * oz * S_COV));
}

// Pass 1: per-batch max|pos| -> partial maxes; also zero-init acc.
// grid (16, B) x 256. Unit-stride float4 loads; per-float4 position mask
// rotates with (tid%3 + it) % 3:
//   m=0: floats (0,1,2,3)=px,py,pz,ox -> max(|x|,|y|,|z|)
//   m=1: floats (4..7)=oy,oz,px',py'  -> max(|z|,|w|)
//   m=2: floats (8..11)=pz',ox'..     -> |x|
__global__ __launch_bounds__(256) void k_bbox(const float* __restrict__ x,
                                              unsigned int* __restrict__ part,
                                              unsigned long long* __restrict__ acc) {
    int b = blockIdx.y;
    int fb = b * 16 + blockIdx.x;             // flat block id 0..1023
    // zero acc: 40960 ull / 1024 blocks = 40 per block
    if (threadIdx.x < 40) acc[fb * 40 + threadIdx.x] = 0ULL;

    const float4* F = (const float4*)(x + (size_t)b * NPTS * 6);  // 98304 per batch
    int tid = blockIdx.x * 256 + threadIdx.x;   // 4096 threads per batch
    int tm = tid % 3;
    float m = 0.0f;
    #pragma unroll
    for (int o = 0; o < 2; ++o) {
        #pragma unroll
        for (int u = 0; u < 12; ++u) {
            int it = o * 12 + u;
            float4 v = F[tid + it * 4096];      // unit stride across lanes
            int mm = tm + (u % 3);              // (tm + it) % 3; 12 % 3 == 0
            mm = mm >= 3 ? mm - 3 : mm;
            float ax = fabsf(v.x), ay = fabsf(v.y), az = fabsf(v.z), aw = fabsf(v.w);
            float c0 = fmaxf(fmaxf(ax, ay), az);
            float c1 = fmaxf(az, aw);
            float cand = mm == 0 ? c0 : (mm == 1 ? c1 : ax);
            m = fmaxf(m, cand);
        }
    }
    for (int off = 32; off > 0; off >>= 1) m = fmaxf(m, __shfl_down(m, off, 64));
    __shared__ float s[4];
    if ((threadIdx.x & 63) == 0) s[threadIdx.x >> 6] = m;
    __syncthreads();
    if (threadIdx.x == 0) {
        m = fmaxf(fmaxf(s[0], s[1]), fmaxf(s[2], s[3]));
        part[fb] = __float_as_uint(m);          // plain store, no init needed
    }
}

// Pass 2: int32 histogram into 16 replicated LDS copies, int64 global flush.
// grid (16, B) x 256. LDS = 640*17*4 = 43520 B -> 3 blocks/CU.
__global__ __launch_bounds__(256) void k_bin(const float* __restrict__ x,
                                             const unsigned int* __restrict__ part,
                                             unsigned long long* __restrict__ acc) {
    __shared__ int h[FEAT * CSTRIDE];
    for (int i = threadIdx.x; i < FEAT * CSTRIDE; i += 256) h[i] = 0;
    int b = blockIdx.y;
    // reduce the 16 partial maxes (uint compare == float compare for >=0)
    unsigned int um = 0u;
    #pragma unroll
    for (int p = 0; p < 16; ++p) um = um > part[b * 16 + p] ? um : part[b * 16 + p];
    float bmax = __uint_as_float(um);
    float thick = fmaxf(2.0f * bmax, 1e-5f);
    float inv_thick = 1.0f / thick;
    __syncthreads();

    const float4* base = (const float4*)(x + (size_t)b * NPTS * 6);
    int tid = blockIdx.x * 256 + threadIdx.x;   // 4096 threads per batch
    int k = threadIdx.x & (COPIES - 1);
    #pragma unroll
    for (int it = 0; it < 8; ++it) {
        int i = tid + it * 4096;
        float4 f0 = base[3 * i + 0];
        float4 f1 = base[3 * i + 1];
        float4 f2 = base[3 * i + 2];
        bin_point(h, k, f0.x, f0.y, f0.z, f0.w, f1.x, f1.y, bmax, inv_thick);
        bin_point(h, k, f1.z, f1.w, f2.x, f2.y, f2.z, f2.w, bmax, inv_thick);
    }
    __syncthreads();
    for (int v = threadIdx.x; v < FEAT; v += 256) {
        long long sum = 0;
        #pragma unroll
        for (int c = 0; c < COPIES; ++c) sum += (long long)h[v * CSTRIDE + c];
        atomicAdd(&acc[b * FEAT + v], (unsigned long long)sum); // native int64
    }
}

// Pass 3: features + L2 normalize. grid B x 640 (one thread per feature).
__global__ __launch_bounds__(640) void k_final(const unsigned long long* __restrict__ acc,
                                               float* __restrict__ out) {
    int b = blockIdx.x;
    int t = threadIdx.x;           // 0..639
    int cell = t / 10, j = t - cell * 10;
    long long ni = (long long)acc[b * FEAT + cell * 10];   // exact count
    long long vi = (long long)acc[b * FEAT + t];
    float n = (float)ni;
    float fc = fmaxf(n, 1.0f);
    float up = 1.0f / sqrtf(fc);
    float val;
    if (j == 0)      val = 0.001f * n * up;
    else if (j < 4)  val = ((float)vi * (1.0f / S_OFF)) * up;
    else             val = ((float)vi * (1.0f / S_COV)) / fc;

    // block reduction of sum(val^2) across 10 waves
    __shared__ float red[12];
    float s = val * val;
    for (int off = 32; off > 0; off >>= 1) s += __shfl_down(s, off, 64);
    if ((t & 63) == 0) red[t >> 6] = s;
    __syncthreads();
    if (t == 0) {
        float tot = 0.0f;
        #pragma unroll
        for (int w = 0; w < 10; ++w) tot += red[w];
        red[10] = fmaxf(sqrtf(tot), 1e-12f);
    }
    __syncthreads();
    out[b * FEAT + t] = val / red[10];
}

extern "C" void kernel_launch(void* const* d_in, const int* in_sizes, int n_in,
                              void* d_out, int out_size, void* d_ws, size_t ws_size,
                              hipStream_t stream) {
    const float* x = (const float*)d_in[0];
    float* out = (float*)d_out;
    unsigned int* part = (unsigned int*)d_ws;
    unsigned long long* acc = (unsigned long long*)((char*)d_ws + 4096);

    dim3 grid(16, BATCH);
    k_bbox<<<grid, 256, 0, stream>>>(x, part, acc);
    k_bin<<<grid, 256, 0, stream>>>(x, part, acc);
    k_final<<<BATCH, 640, 0, stream>>>(acc, out);
}

// Round 6
// 162.128 us; speedup vs baseline: 1.0200x; 1.0200x over previous
//
#include <hip/hip_runtime.h>

// HandcraftedPodExtractor: 3D cell binning + normalized feature vector.
// Input  x: (64, 65536, 6) fp32  [pos(3) | ori(3)] interleaved per point.
// Output  : (64, 640) fp32.
//
// R5 post-mortem: k_bbox load-pattern rewrite was a no-op -> k_bbox was
// already BW-bound (~16us). R6 theory: k_bin's 43.5KB LDS caps it at
// 3 blocks/CU -> only 768/1024 blocks co-resident -> 256-block tail at
// 1/3 utilization (~1.7x makespan). Fix: LDS = 640*16*4 = 40960B exactly
// -> 4 blocks/CU -> all 1024 blocks in one dispatch wave. Unpadded
// stride-16 would collapse banks (160 floats % 32 banks == 0), so copy
// index is XOR-swizzled: k' = k ^ (cell & 15) -> same-k lanes with
// different cells hit distinct banks; dcell=16 aliases are 2-way (free).
//
// Fixed-point scales:
//   offsets: round(off * 2^18)  (|off|<=~0.13 -> per-pt<2^15, blk-sum<2^27)
//   cov:     round(v  * 2^12)  (per-pt<2^18 at 5.6-sigma, blk-sum<2^31)
// Output quantization error ~1e-6..1e-4, threshold 5.9e-3.
//
// ws layout:
//   [0,    4096)           : part_max[B*16] as uint bits (nonneg floats)
//   [4096, 4096 + 327680)  : acc[B][640] int64

#define BATCH 64
#define NPTS 65536
#define FEAT 640          // 64 cells * 10 values
#define COPIES 16         // replicated LDS histograms, XOR-swizzled
#define CSTRIDE 16        // copy stride (no pad; swizzle handles banks)
#define S_OFF 262144.0f   // 2^18
#define S_COV 4096.0f     // 2^12

__device__ __forceinline__ void bin_point(int* h, int k,
                                          float px, float py, float pz,
                                          float ox, float oy, float oz,
                                          float bmax, float inv_thick) {
    float sx = (px + bmax) * inv_thick;
    float sy = (py + bmax) * inv_thick;
    float sz = (pz + bmax) * inv_thick;
    int cx = (int)(sx * 4.0f); cx = cx < 0 ? 0 : (cx > 3 ? 3 : cx);
    int cy = (int)(sy * 4.0f); cy = cy < 0 ? 0 : (cy > 3 ? 3 : cy);
    int cz = (int)(sz * 4.0f); cz = cz < 0 ? 0 : (cz > 3 ? 3 : cz);
    int cell = (cx * 4 + cy) * 4 + cz;
    float offx = sx - (cx * 0.25f + 0.125f);
    float offy = sy - (cy * 0.25f + 0.125f);
    float offz = sz - (cz * 0.25f + 0.125f);
    // XOR bank swizzle: stride-16 copies alias banks by cell; k^(cell&15)
    // de-aliases same-k lanes across cells.
    int kk = k ^ (cell & 15);
    int a = cell * (10 * CSTRIDE) + kk;
    atomicAdd(&h[a + 0 * CSTRIDE], 1);
    atomicAdd(&h[a + 1 * CSTRIDE], __float2int_rn(offx * S_OFF));
    atomicAdd(&h[a + 2 * CSTRIDE], __float2int_rn(offy * S_OFF));
    atomicAdd(&h[a + 3 * CSTRIDE], __float2int_rn(offz * S_OFF));
    atomicAdd(&h[a + 4 * CSTRIDE], __float2int_rn(ox * ox * S_COV));
    atomicAdd(&h[a + 5 * CSTRIDE], __float2int_rn(ox * oy * S_COV));
    atomicAdd(&h[a + 6 * CSTRIDE], __float2int_rn(ox * oz * S_COV));
    atomicAdd(&h[a + 7 * CSTRIDE], __float2int_rn(oy * oy * S_COV));
    atomicAdd(&h[a + 8 * CSTRIDE], __float2int_rn(oy * oz * S_COV));
    atomicAdd(&h[a + 9 * CSTRIDE], __float2int_rn(oz * oz * S_COV));
}

// Pass 1: per-batch max|pos| -> partial maxes; also zero-init acc.
// grid (16, B) x 256. Unit-stride float4 loads; position mask rotates
// with (tid%3 + it) % 3.
__global__ __launch_bounds__(256) void k_bbox(const float* __restrict__ x,
                                              unsigned int* __restrict__ part,
                                              unsigned long long* __restrict__ acc) {
    int b = blockIdx.y;
    int fb = b * 16 + blockIdx.x;             // flat block id 0..1023
    if (threadIdx.x < 40) acc[fb * 40 + threadIdx.x] = 0ULL;

    const float4* F = (const float4*)(x + (size_t)b * NPTS * 6);  // 98304 per batch
    int tid = blockIdx.x * 256 + threadIdx.x;   // 4096 threads per batch
    int tm = tid % 3;
    float m = 0.0f;
    #pragma unroll
    for (int o = 0; o < 2; ++o) {
        #pragma unroll
        for (int u = 0; u < 12; ++u) {
            int it = o * 12 + u;
            float4 v = F[tid + it * 4096];      // unit stride across lanes
            int mm = tm + (u % 3);              // (tm + it) % 3; 12 % 3 == 0
            mm = mm >= 3 ? mm - 3 : mm;
            float ax = fabsf(v.x), ay = fabsf(v.y), az = fabsf(v.z), aw = fabsf(v.w);
            float c0 = fmaxf(fmaxf(ax, ay), az);
            float c1 = fmaxf(az, aw);
            float cand = mm == 0 ? c0 : (mm == 1 ? c1 : ax);
            m = fmaxf(m, cand);
        }
    }
    for (int off = 32; off > 0; off >>= 1) m = fmaxf(m, __shfl_down(m, off, 64));
    __shared__ float s[4];
    if ((threadIdx.x & 63) == 0) s[threadIdx.x >> 6] = m;
    __syncthreads();
    if (threadIdx.x == 0) {
        m = fmaxf(fmaxf(s[0], s[1]), fmaxf(s[2], s[3]));
        part[fb] = __float_as_uint(m);          // plain store, no init needed
    }
}

// Pass 2: int32 histogram into 16 XOR-swizzled LDS copies, int64 flush.
// grid (16, B) x 256. LDS = 640*16*4 = 40960 B -> 4 blocks/CU ->
// all 1024 blocks co-resident (no dispatch tail).
__global__ __launch_bounds__(256) void k_bin(const float* __restrict__ x,
                                             const unsigned int* __restrict__ part,
                                             unsigned long long* __restrict__ acc) {
    __shared__ int h[FEAT * CSTRIDE];
    for (int i = threadIdx.x; i < FEAT * CSTRIDE; i += 256) h[i] = 0;
    int b = blockIdx.y;
    // reduce the 16 partial maxes (uint compare == float compare for >=0)
    unsigned int um = 0u;
    #pragma unroll
    for (int p = 0; p < 16; ++p) um = um > part[b * 16 + p] ? um : part[b * 16 + p];
    float bmax = __uint_as_float(um);
    float thick = fmaxf(2.0f * bmax, 1e-5f);
    float inv_thick = 1.0f / thick;
    __syncthreads();

    const float4* base = (const float4*)(x + (size_t)b * NPTS * 6);
    int tid = blockIdx.x * 256 + threadIdx.x;   // 4096 threads per batch
    int k = threadIdx.x & (COPIES - 1);
    #pragma unroll
    for (int it = 0; it < 8; ++it) {
        int i = tid + it * 4096;
        float4 f0 = base[3 * i + 0];
        float4 f1 = base[3 * i + 1];
        float4 f2 = base[3 * i + 2];
        bin_point(h, k, f0.x, f0.y, f0.z, f0.w, f1.x, f1.y, bmax, inv_thick);
        bin_point(h, k, f1.z, f1.w, f2.x, f2.y, f2.z, f2.w, bmax, inv_thick);
    }
    __syncthreads();
    for (int v = threadIdx.x; v < FEAT; v += 256) {
        long long sum = 0;
        #pragma unroll
        for (int c = 0; c < COPIES; ++c) sum += (long long)h[v * CSTRIDE + c];
        atomicAdd(&acc[b * FEAT + v], (unsigned long long)sum); // native int64
    }
}

// Pass 3: features + L2 normalize. grid B x 640 (one thread per feature).
__global__ __launch_bounds__(640) void k_final(const unsigned long long* __restrict__ acc,
                                               float* __restrict__ out) {
    int b = blockIdx.x;
    int t = threadIdx.x;           // 0..639
    int cell = t / 10, j = t - cell * 10;
    long long ni = (long long)acc[b * FEAT + cell * 10];   // exact count
    long long vi = (long long)acc[b * FEAT + t];
    float n = (float)ni;
    float fc = fmaxf(n, 1.0f);
    float up = 1.0f / sqrtf(fc);
    float val;
    if (j == 0)      val = 0.001f * n * up;
    else if (j < 4)  val = ((float)vi * (1.0f / S_OFF)) * up;
    else             val = ((float)vi * (1.0f / S_COV)) / fc;

    // block reduction of sum(val^2) across 10 waves
    __shared__ float red[12];
    float s = val * val;
    for (int off = 32; off > 0; off >>= 1) s += __shfl_down(s, off, 64);
    if ((t & 63) == 0) red[t >> 6] = s;
    __syncthreads();
    if (t == 0) {
        float tot = 0.0f;
        #pragma unroll
        for (int w = 0; w < 10; ++w) tot += red[w];
        red[10] = fmaxf(sqrtf(tot), 1e-12f);
    }
    __syncthreads();
    out[b * FEAT + t] = val / red[10];
}

extern "C" void kernel_launch(void* const* d_in, const int* in_sizes, int n_in,
                              void* d_out, int out_size, void* d_ws, size_t ws_size,
                              hipStream_t stream) {
    const float* x = (const float*)d_in[0];
    float* out = (float*)d_out;
    unsigned int* part = (unsigned int*)d_ws;
    unsigned long long* acc = (unsigned long long*)((char*)d_ws + 4096);

    dim3 grid(16, BATCH);
    k_bbox<<<grid, 256, 0, stream>>>(x, part, acc);
    k_bin<<<grid, 256, 0, stream>>>(x, part, acc);
    k_final<<<BATCH, 640, 0, stream>>>(acc, out);
}